// Round 10
// baseline (483.886 us; speedup 1.0000x reference)
//
#include <hip/hip_runtime.h>

#define BATCH 8192
#define FEAT  512
#define NID   256
#define NTR   256
#define HID   1024
#define PPF   47       // params per transform feature (3*16-1)
#define PPFP  48       // padded to 48
#define NOUT  (NTR*PPF)    // 12032
#define TBOUND 3.0f
#define MIN_W 0.001f
#define MIN_H 0.001f
#define MIN_D 0.001f

typedef __bf16 bf16x8 __attribute__((ext_vector_type(8)));
typedef float  f32x4  __attribute__((ext_vector_type(4)));

__device__ __forceinline__ unsigned short f2bf(float f) {
  unsigned u = __float_as_uint(f);
  u += 0x7FFFu + ((u >> 16) & 1u);   // RNE
  return (unsigned short)(u >> 16);
}

// async global->LDS, 16B per lane. LDS dest must be wave-uniform base
// (HW adds lane*16); global source is per-lane.
__device__ __forceinline__ void gload16(const void* g, void* l) {
  __builtin_amdgcn_global_load_lds(
      (const __attribute__((address_space(1))) void*)g,
      (__attribute__((address_space(3))) void*)l, 16, 0, 0);
}

// ---------------- pack kernels ----------------

__global__ void k_pack_inputs(const float* __restrict__ in,
                              unsigned short* __restrict__ idbf,
                              float* __restrict__ outp) {
  int b = blockIdx.x;
  int j = threadIdx.x;            // 0..255
  float v = in[b * FEAT + 2 * j + 1];
  idbf[b * NID + j] = f2bf(v);
  outp[b * FEAT + 2 * j + 1] = v;
}

// W1 [256][1024] f32 -> W1T [1024][256] bf16
__global__ void k_pack_w1t(const float* __restrict__ W1,
                           unsigned short* __restrict__ W1T) {
  __shared__ unsigned short tl[64][65];
  int n0 = blockIdx.x * 64, k0 = blockIdx.y * 64;
  int c = threadIdx.x & 63, r4 = threadIdx.x >> 6;
  #pragma unroll
  for (int i = 0; i < 16; ++i) {
    int kk = r4 + i * 4;
    tl[kk][c] = f2bf(W1[(k0 + kk) * HID + n0 + c]);
  }
  __syncthreads();
  #pragma unroll
  for (int i = 0; i < 16; ++i) {
    int nn = r4 + i * 4;
    W1T[(n0 + nn) * NID + k0 + c] = tl[c][nn];
  }
}

// W2 [1024][12032] f32 -> W2T [12288][1024] bf16 (padded)
__global__ void k_pack_w2t(const float* __restrict__ W2,
                           unsigned short* __restrict__ W2T) {
  __shared__ unsigned short tl[64][65];
  int ns0 = blockIdx.x * 64, k0 = blockIdx.y * 64;
  int c = threadIdx.x & 63, r4 = threadIdx.x >> 6;
  #pragma unroll
  for (int i = 0; i < 16; ++i) {
    int kk = r4 + i * 4;
    tl[kk][c] = f2bf(W2[(k0 + kk) * (long)NOUT + ns0 + c]);
  }
  __syncthreads();
  #pragma unroll
  for (int i = 0; i < 16; ++i) {
    int nn = r4 + i * 4;
    int ns = ns0 + nn;
    int nd = (ns / PPF) * PPFP + (ns % PPF);
    W2T[(long)nd * HID + k0 + c] = tl[c][nn];
  }
}

__global__ void k_pad_w2t(unsigned short* __restrict__ W2T) {
  int idx = blockIdx.x * 256 + threadIdx.x;  // 256 features * 1024 k
  int f = idx >> 10, k = idx & 1023;
  W2T[((long)(f * PPFP + PPF)) * HID + k] = 0;
}

// ---------------- GEMM1: h = relu(idbf @ W1 + b1), bf16 out ----------------
// M=8192 K=256 N=1024, tiles 128x128, BK=64, 4 waves (2x2), dbuf 2-phase
__global__ __launch_bounds__(256, 2) void k_gemm1(
    const unsigned short* __restrict__ A, const unsigned short* __restrict__ Bw,
    const float* __restrict__ b1, unsigned short* __restrict__ H) {
  __shared__ __align__(16) char sm[65536];  // 2 x (A 16KB + B 16KB)
  const int tid = threadIdx.x;
  const int lane = tid & 63, wid = tid >> 6;
  const int c = lane & 15, g = lane >> 4;
  const int wm = wid >> 1, wn = wid & 1;
  const int m0 = blockIdx.x * 128, n0 = blockIdx.y * 128;

  f32x4 zero = {0.f, 0.f, 0.f, 0.f};
  f32x4 acc[4][4];
  #pragma unroll
  for (int a = 0; a < 4; ++a)
    #pragma unroll
    for (int b = 0; b < 4; ++b) acc[a][b] = zero;

  #define G1_STAGE(half, ks)                                                   \
    {                                                                          \
      char* bA = sm + (half) * 32768;                                          \
      char* bB = bA + 16384;                                                   \
      _Pragma("unroll")                                                        \
      for (int j = 0; j < 4; ++j) {                                            \
        int s0 = j * 256 + wid * 64;                                           \
        int s = s0 + lane;                                                     \
        int row = s >> 3, kb = (s & 7) ^ (row & 7);                            \
        gload16(A + (long)(m0 + row) * NID + (ks) * 64 + kb * 8, bA + s0 * 16);\
        gload16(Bw + (long)(n0 + row) * NID + (ks) * 64 + kb * 8, bB + s0 * 16);\
      }                                                                        \
    }

  G1_STAGE(0, 0);
  __syncthreads();
  for (int ks = 0; ks < 4; ++ks) {
    int cur = ks & 1;
    if (ks < 3) G1_STAGE(cur ^ 1, ks + 1);
    char* bA = sm + cur * 32768;
    char* bB = bA + 16384;
    #pragma unroll
    for (int kk = 0; kk < 2; ++kk) {
      bf16x8 av[4], bv[4];
      int kbl = kk * 4 + g;
      #pragma unroll
      for (int mf = 0; mf < 4; ++mf) {
        int row = wm * 64 + mf * 16 + c;
        av[mf] = *(const bf16x8*)(bA + row * 128 + ((kbl ^ (row & 7)) << 4));
      }
      #pragma unroll
      for (int nf = 0; nf < 4; ++nf) {
        int col = wn * 64 + nf * 16 + c;
        bv[nf] = *(const bf16x8*)(bB + col * 128 + ((kbl ^ (col & 7)) << 4));
      }
      #pragma unroll
      for (int mf = 0; mf < 4; ++mf)
        #pragma unroll
        for (int nf = 0; nf < 4; ++nf)
          acc[mf][nf] = __builtin_amdgcn_mfma_f32_16x16x32_bf16(
              av[mf], bv[nf], acc[mf][nf], 0, 0, 0);
    }
    __syncthreads();
  }
  #pragma unroll
  for (int nf = 0; nf < 4; ++nf) {
    float bb = b1[n0 + wn * 64 + nf * 16 + c];
    #pragma unroll
    for (int mf = 0; mf < 4; ++mf) {
      #pragma unroll
      for (int i = 0; i < 4; ++i) {
        int row = m0 + wm * 64 + mf * 16 + 4 * g + i;
        int col = n0 + wn * 64 + nf * 16 + c;
        float v = acc[mf][nf][i] + bb;
        H[(long)row * HID + col] = f2bf(fmaxf(v, 0.f));
      }
    }
  }
}

// ---------------- GEMM2 (params) fused with per-lane spline ----------------
// M=8192, Npad=12288, K=1024. Tile 128x384 (8 features), BK=32, 8 waves
// (2x4), wave = 64 rows x 96 cols (2 features). LDS-byte-optimal geometry:
// per block-ks traffic 80KB read + 32KB write (-27% vs 128x192/BK64) with
// identical per-CU barrier count. Dbuf 2x32KB; alloc 68KB -> 2 blocks/CU.
// 64B-row swizzle (R9-verified): phys slot p of row r holds k-chunk
// p ^ ((r>>1)&3); reads use slot g ^ ((c>>1)&3) -> uniform 2-way (free).
__global__ __launch_bounds__(512, 4) void k_gemm2_spline(
    const unsigned short* __restrict__ Hb, const unsigned short* __restrict__ W2T,
    const float* __restrict__ b2, const float* __restrict__ inp,
    float* __restrict__ outp, float* __restrict__ ladw) {
  __shared__ __align__(16) char sm[69632];  // K-loop 64KB; epilogue 68KB
  const int tid = threadIdx.x;
  const int lane = tid & 63, wid = tid >> 6;
  const int c = lane & 15, g = lane >> 4;
  const int wm = wid >> 2, wn = wid & 3;
  const long m0 = (long)blockIdx.x * 128;
  const int bn = blockIdx.y;
  const int n0 = bn * 384;  // padded-col base

  f32x4 zero = {0.f, 0.f, 0.f, 0.f};
  f32x4 acc[4][6];
  #pragma unroll
  for (int a = 0; a < 4; ++a)
    #pragma unroll
    for (int b = 0; b < 6; ++b) acc[a][b] = zero;

  // ---- staging (pre-swizzled global src, linear wave-uniform LDS dest) ----
  // A: 512 slots (128 rows x 4 chunks) -> 1/thread. B: 1536 slots -> 3/thread.
  const char *gA, *gB0, *gB1, *gB2;
  {
    int rA = tid >> 2, pA = tid & 3, kA = pA ^ ((rA >> 1) & 3);
    gA = (const char*)(Hb + (m0 + rA) * 1024L + kA * 8);
    int s0 = tid,        r0 = s0 >> 2, k0 = (s0 & 3) ^ ((r0 >> 1) & 3);
    int s1 = 512 + tid,  r1 = s1 >> 2, k1 = (s1 & 3) ^ ((r1 >> 1) & 3);
    int s2 = 1024 + tid, r2 = s2 >> 2, k2 = (s2 & 3) ^ ((r2 >> 1) & 3);
    gB0 = (const char*)(W2T + (long)(n0 + r0) * 1024L + k0 * 8);
    gB1 = (const char*)(W2T + (long)(n0 + r1) * 1024L + k1 * 8);
    gB2 = (const char*)(W2T + (long)(n0 + r2) * 1024L + k2 * 8);
  }
  // ds_read byte offsets (buffer-relative); mf/nf deltas imm-foldable
  const int slot16 = (g ^ ((c >> 1) & 3)) << 4;
  const int oA = (wm * 64 + c) * 64 + slot16;
  const int oB = 8192 + (wn * 96 + c) * 64 + slot16;

  #define G2_STAGE(HALF, IMM)                                              \
    {                                                                      \
      gload16(gA + (IMM), sm + (HALF) * 32768 + wid * 1024);               \
      gload16(gB0 + (IMM), sm + (HALF) * 32768 + 8192 + wid * 1024);       \
      gload16(gB1 + (IMM), sm + (HALF) * 32768 + 16384 + wid * 1024);      \
      gload16(gB2 + (IMM), sm + (HALF) * 32768 + 24576 + wid * 1024);      \
    }

  #define G2_BUMP(N) { gA += (N); gB0 += (N); gB1 += (N); gB2 += (N); }

  #define G2_COMP(HALF)                                                    \
    {                                                                      \
      bf16x8 av[4], bv[6];                                                 \
      _Pragma("unroll")                                                    \
      for (int mf = 0; mf < 4; ++mf)                                       \
        av[mf] = *(const bf16x8*)(sm + (HALF) * 32768 + oA + mf * 1024);   \
      _Pragma("unroll")                                                    \
      for (int nf = 0; nf < 6; ++nf)                                       \
        bv[nf] = *(const bf16x8*)(sm + (HALF) * 32768 + oB + nf * 1024);   \
      _Pragma("unroll")                                                    \
      for (int mf = 0; mf < 4; ++mf)                                       \
        _Pragma("unroll")                                                  \
        for (int nf = 0; nf < 6; ++nf)                                     \
          acc[mf][nf] = __builtin_amdgcn_mfma_f32_16x16x32_bf16(           \
              av[mf], bv[nf], acc[mf][nf], 0, 0, 0);                       \
    }

  // 32 K-steps of 32. prologue: stage ks=0 -> half0.
  G2_STAGE(0, 0);
  __syncthreads();
  for (int p = 0; p < 15; ++p) {
    G2_STAGE(1, 64);       // stage ks=2p+1 -> half1
    G2_COMP(0);            // compute ks=2p
    __syncthreads();
    G2_STAGE(0, 128);      // stage ks=2p+2 -> half0
    G2_COMP(1);            // compute ks=2p+1
    __syncthreads();
    G2_BUMP(128);
  }
  G2_STAGE(1, 64);         // stage ks=31 -> half1
  G2_COMP(0);              // compute ks=30
  __syncthreads();
  G2_COMP(1);              // compute ks=31
  __syncthreads();         // epilogue stripes overlay the double buffer

  // ---- epilogue: per-wave f32 LDS stripes, 2 features serially ----
  // stripe layout: [param k 0..15][row 0..63], k-stride 68 f32
  float* stA = (float*)(sm + wid * 8704);     // 4352 B
  float* stB = stA + 1088;                    // 4352 B
  const long r = m0 + wm * 64 + lane;

  #pragma unroll
  for (int f = 0; f < 2; ++f) {
    const int t = bn * 8 + wn * 2 + f;        // global transform-feature id
    const float* b2t = b2 + t * PPF;
    const float bw = b2t[c];
    const float bh = b2t[16 + c];
    const float bd = (c < 15) ? b2t[32 + c] : 0.f;
    float x = inp[r * FEAT + 2 * t];          // issue early

    // stage widths -> stA, heights -> stB (b128, conflict-free)
    // (same-wave program order guarantees f=0 reads precede f=1 writes)
    #pragma unroll
    for (int mf = 0; mf < 4; ++mf) {
      f32x4 vw = acc[mf][f * 3 + 0], vh = acc[mf][f * 3 + 1];
      #pragma unroll
      for (int i = 0; i < 4; ++i) { vw[i] += bw; vh[i] += bh; }
      *(f32x4*)(stA + c * 68 + mf * 16 + 4 * g) = vw;
      *(f32x4*)(stB + c * 68 + mf * 16 + 4 * g) = vh;
    }

    float xc = fminf(fmaxf(x, -TBOUND), TBOUND);
    int idx = 0;
    float in_cw, in_w, in_ch, in_h;
    // ---- widths: softmax + fused cumsum/bin-search ----
    {
      float u[16];
      #pragma unroll
      for (int k = 0; k < 16; ++k) u[k] = stA[k * 68 + lane];
      float mx = u[0];
      #pragma unroll
      for (int k = 1; k < 16; ++k) mx = fmaxf(mx, u[k]);
      float e[16], s = 0.f;
      #pragma unroll
      for (int k = 0; k < 16; ++k) { e[k] = __expf(u[k] - mx); s += e[k]; }
      float inv = (1.f - MIN_W * 16.f) / s;
      float wk = fmaf(e[0], inv, MIN_W);
      float wsel = wk, cum = 0.f;
      in_cw = -TBOUND;
      #pragma unroll
      for (int k = 0; k < 15; ++k) {
        cum += wk;
        float knot = fmaf(2.f * TBOUND, cum, -TBOUND);
        float wk1 = fmaf(e[k + 1], inv, MIN_W);
        bool le = (knot <= xc);
        idx = le ? k + 1 : idx;
        in_cw = le ? knot : in_cw;
        wsel = le ? wk1 : wsel;
        wk = wk1;
      }
      in_w = 2.f * TBOUND * wsel;
    }
    // stage derivs -> stA (same-wave, program-ordered after reads)
    #pragma unroll
    for (int mf = 0; mf < 4; ++mf) {
      f32x4 vd = acc[mf][f * 3 + 2];
      #pragma unroll
      for (int i = 0; i < 4; ++i) vd[i] += bd;
      *(f32x4*)(stA + c * 68 + mf * 16 + 4 * g) = vd;
    }
    // ---- heights: softmax + select-at-idx ----
    {
      float u[16];
      #pragma unroll
      for (int k = 0; k < 16; ++k) u[k] = stB[k * 68 + lane];
      float mx = u[0];
      #pragma unroll
      for (int k = 1; k < 16; ++k) mx = fmaxf(mx, u[k]);
      float e[16], s = 0.f;
      #pragma unroll
      for (int k = 0; k < 16; ++k) { e[k] = __expf(u[k] - mx); s += e[k]; }
      float inv = (1.f - MIN_H * 16.f) / s;
      float hk = fmaf(e[0], inv, MIN_H);
      float hsel = hk, cum = 0.f;
      in_ch = -TBOUND;
      #pragma unroll
      for (int k = 0; k < 15; ++k) {
        cum += hk;
        float knot = fmaf(2.f * TBOUND, cum, -TBOUND);
        float hk1 = fmaf(e[k + 1], inv, MIN_H);
        bool pick = (idx == k + 1);
        in_ch = pick ? knot : in_ch;
        hsel = pick ? hk1 : hsel;
        hk = hk1;
      }
      in_h = 2.f * TBOUND * hsel;
    }
    // ---- derivs: 2 runtime-indexed LDS reads + 2 softplus ----
    float d0, d1;
    {
      int i0 = (idx > 0) ? idx - 1 : 0;
      int i1 = (idx < 15) ? idx : 14;
      float v0 = stA[i0 * 68 + lane];
      float v1 = stA[i1 * 68 + lane];
      float sp0 = (v0 > 0.f) ? (v0 + log1pf(__expf(-v0))) : log1pf(__expf(v0));
      float sp1 = (v1 > 0.f) ? (v1 + log1pf(__expf(-v1))) : log1pf(__expf(v1));
      d0 = (idx == 0) ? 1.f : (MIN_D + sp0);
      d1 = (idx == 15) ? 1.f : (MIN_D + sp1);
    }
    // ---- rational-quadratic eval ----
    float dlt = in_h / in_w;
    float th = (xc - in_cw) / in_w;
    float omt = 1.f - th, t1m = th * omt;
    float den = dlt + (d0 + d1 - 2.f * dlt) * t1m;
    float num = in_h * (dlt * th * th + d0 * t1m);
    float y = in_ch + num / den;
    float dn = dlt * dlt * (d1 * th * th + 2.f * dlt * t1m + d0 * omt * omt);
    float lad = __logf(dn) - 2.f * __logf(den);
    bool inside = (x >= -TBOUND) && (x <= TBOUND);
    y = inside ? y : x;
    lad = inside ? lad : 0.f;
    outp[r * FEAT + 2 * t] = y;
    ladw[r * NTR + t] = lad;
  }
}

// ---------------- lad reduction: 256 -> 1 per batch row ----------------
__global__ void k_reduce_lad(const float* __restrict__ ladw,
                             float* __restrict__ lado) {
  int wid = threadIdx.x >> 6, lane = threadIdx.x & 63;
  long b = (long)blockIdx.x * 4 + wid;
  const float4* p = (const float4*)(ladw + b * NTR);
  float4 v = p[lane];
  float s = v.x + v.y + v.z + v.w;
  #pragma unroll
  for (int d = 1; d < 64; d <<= 1) s += __shfl_xor(s, d, 64);
  if (lane == 0) lado[b] = s;
}

extern "C" void kernel_launch(void* const* d_in, const int* in_sizes, int n_in,
                              void* d_out, int out_size, void* d_ws, size_t ws_size,
                              hipStream_t stream) {
  const float* inp = (const float*)d_in[0];
  const float* W1  = (const float*)d_in[1];
  const float* b1  = (const float*)d_in[2];
  const float* W2  = (const float*)d_in[3];
  const float* b2  = (const float*)d_in[4];
  float* outp = (float*)d_out;
  float* lado = outp + (long)BATCH * FEAT;

  // workspace layout (~52.5 MB)
  char* ws = (char*)d_ws;
  unsigned short* Hb   = (unsigned short*)(ws);              // 16,777,216 B
  unsigned short* idbf = (unsigned short*)(ws + 16777216);   //  4,194,304 B
  unsigned short* W1T  = (unsigned short*)(ws + 20971520);   //    524,288 B
  unsigned short* W2T  = (unsigned short*)(ws + 21495808);   // 25,165,824 B
  float*          ladw = (float*)(ws + 46661632);            //  8,388,608 B

  k_pack_inputs<<<dim3(BATCH), dim3(256), 0, stream>>>(inp, idbf, outp);
  k_pack_w1t<<<dim3(16, 4), dim3(256), 0, stream>>>(W1, W1T);
  k_pack_w2t<<<dim3(188, 16), dim3(256), 0, stream>>>(W2, W2T);
  k_pad_w2t<<<dim3(1024), dim3(256), 0, stream>>>(W2T);
  k_gemm1<<<dim3(64, 8), dim3(256), 0, stream>>>(idbf, W1T, b1, Hb);
  k_gemm2_spline<<<dim3(64, 32), dim3(512), 0, stream>>>(Hb, W2T, b2, inp, outp, ladw);
  k_reduce_lad<<<dim3(2048), dim3(256), 0, stream>>>(ladw, lado);
}

// Round 11
// 228.878 us; speedup vs baseline: 2.1142x; 2.1142x over previous
//
#include <hip/hip_runtime.h>

#define BATCH 8192
#define FEAT  512
#define NID   256
#define NTR   256
#define HID   1024
#define PPF   47       // params per transform feature (3*16-1)
#define PPFP  48       // padded to 48
#define NOUT  (NTR*PPF)    // 12032
#define TBOUND 3.0f
#define MIN_W 0.001f
#define MIN_H 0.001f
#define MIN_D 0.001f

typedef __bf16 bf16x8 __attribute__((ext_vector_type(8)));
typedef float  f32x4  __attribute__((ext_vector_type(4)));

__device__ __forceinline__ unsigned short f2bf(float f) {
  unsigned u = __float_as_uint(f);
  u += 0x7FFFu + ((u >> 16) & 1u);   // RNE
  return (unsigned short)(u >> 16);
}

// async global->LDS, 16B per lane. LDS dest must be wave-uniform base
// (HW adds lane*16); global source is per-lane.
__device__ __forceinline__ void gload16(const void* g, void* l) {
  __builtin_amdgcn_global_load_lds(
      (const __attribute__((address_space(1))) void*)g,
      (__attribute__((address_space(3))) void*)l, 16, 0, 0);
}

// ---------------- fused pack kernel ----------------
// bid [0,4096):   inputs -> idbf (bf16) + outp full-row copy (float4)
// bid [4096,4160): W1 -> W1T transpose (bf16)
// bid [4160,7168): W2 -> W2T transpose+pad-remap (bf16)
// bid [7168,8192): zero pad column 47 of each 48-group
__global__ void k_pack_all(const float* __restrict__ in,
                           const float* __restrict__ W1,
                           const float* __restrict__ W2,
                           unsigned short* __restrict__ idbf,
                           unsigned short* __restrict__ W1T,
                           unsigned short* __restrict__ W2T,
                           float* __restrict__ outp) {
  const int bid = blockIdx.x;
  const int tid = threadIdx.x;
  if (bid < 4096) {
    // 2 rows per block; full float4 row copy into outp (even cols are
    // overwritten by gemm2's spline output later), odd cols -> idbf bf16.
    int b = bid * 2 + (tid >> 7);
    int j4 = tid & 127;                       // float4 index within row
    float4 v = ((const float4*)(in + (long)b * FEAT))[j4];
    ((float4*)(outp + (long)b * FEAT))[j4] = v;
    ushort2 h;
    h.x = f2bf(v.y);
    h.y = f2bf(v.w);
    ((ushort2*)(idbf + (long)b * NID))[j4] = h;
  } else if (bid < 4160) {
    __shared__ unsigned short tl[64][65];
    int i = bid - 4096;
    int n0 = (i & 15) * 64, k0 = (i >> 4) * 64;
    int c = tid & 63, r4 = tid >> 6;
    #pragma unroll
    for (int j = 0; j < 16; ++j) {
      int kk = r4 + j * 4;
      tl[kk][c] = f2bf(W1[(k0 + kk) * HID + n0 + c]);
    }
    __syncthreads();
    #pragma unroll
    for (int j = 0; j < 16; ++j) {
      int nn = r4 + j * 4;
      W1T[(n0 + nn) * NID + k0 + c] = tl[c][nn];
    }
  } else if (bid < 7168) {
    __shared__ unsigned short tl[64][65];
    int i = bid - 4160;
    int ns0 = (i % 188) * 64, k0 = (i / 188) * 64;
    int c = tid & 63, r4 = tid >> 6;
    #pragma unroll
    for (int j = 0; j < 16; ++j) {
      int kk = r4 + j * 4;
      tl[kk][c] = f2bf(W2[(k0 + kk) * (long)NOUT + ns0 + c]);
    }
    __syncthreads();
    #pragma unroll
    for (int j = 0; j < 16; ++j) {
      int nn = r4 + j * 4;
      int ns = ns0 + nn;
      int nd = (ns / PPF) * PPFP + (ns % PPF);
      W2T[(long)nd * HID + k0 + c] = tl[c][nn];
    }
  } else {
    int idx = (bid - 7168) * 256 + tid;       // 256 features * 1024 k
    int f = idx >> 10, k = idx & 1023;
    W2T[((long)(f * PPFP + PPF)) * HID + k] = 0;
  }
}

// ---------------- GEMM1: h = relu(idbf @ W1 + b1), bf16 out ----------------
// M=8192 K=256 N=1024, tiles 128x128, BK=64, 4 waves (2x2), dbuf 2-phase
__global__ __launch_bounds__(256, 2) void k_gemm1(
    const unsigned short* __restrict__ A, const unsigned short* __restrict__ Bw,
    const float* __restrict__ b1, unsigned short* __restrict__ H) {
  __shared__ __align__(16) char sm[65536];  // 2 x (A 16KB + B 16KB)
  const int tid = threadIdx.x;
  const int lane = tid & 63, wid = tid >> 6;
  const int c = lane & 15, g = lane >> 4;
  const int wm = wid >> 1, wn = wid & 1;
  const int m0 = blockIdx.x * 128, n0 = blockIdx.y * 128;

  f32x4 zero = {0.f, 0.f, 0.f, 0.f};
  f32x4 acc[4][4];
  #pragma unroll
  for (int a = 0; a < 4; ++a)
    #pragma unroll
    for (int b = 0; b < 4; ++b) acc[a][b] = zero;

  #define G1_STAGE(half, ks)                                                   \
    {                                                                          \
      char* bA = sm + (half) * 32768;                                          \
      char* bB = bA + 16384;                                                   \
      _Pragma("unroll")                                                        \
      for (int j = 0; j < 4; ++j) {                                            \
        int s0 = j * 256 + wid * 64;                                           \
        int s = s0 + lane;                                                     \
        int row = s >> 3, kb = (s & 7) ^ (row & 7);                            \
        gload16(A + (long)(m0 + row) * NID + (ks) * 64 + kb * 8, bA + s0 * 16);\
        gload16(Bw + (long)(n0 + row) * NID + (ks) * 64 + kb * 8, bB + s0 * 16);\
      }                                                                        \
    }

  G1_STAGE(0, 0);
  __syncthreads();
  for (int ks = 0; ks < 4; ++ks) {
    int cur = ks & 1;
    if (ks < 3) G1_STAGE(cur ^ 1, ks + 1);
    char* bA = sm + cur * 32768;
    char* bB = bA + 16384;
    #pragma unroll
    for (int kk = 0; kk < 2; ++kk) {
      bf16x8 av[4], bv[4];
      int kbl = kk * 4 + g;
      #pragma unroll
      for (int mf = 0; mf < 4; ++mf) {
        int row = wm * 64 + mf * 16 + c;
        av[mf] = *(const bf16x8*)(bA + row * 128 + ((kbl ^ (row & 7)) << 4));
      }
      #pragma unroll
      for (int nf = 0; nf < 4; ++nf) {
        int col = wn * 64 + nf * 16 + c;
        bv[nf] = *(const bf16x8*)(bB + col * 128 + ((kbl ^ (col & 7)) << 4));
      }
      #pragma unroll
      for (int mf = 0; mf < 4; ++mf)
        #pragma unroll
        for (int nf = 0; nf < 4; ++nf)
          acc[mf][nf] = __builtin_amdgcn_mfma_f32_16x16x32_bf16(
              av[mf], bv[nf], acc[mf][nf], 0, 0, 0);
    }
    __syncthreads();
  }
  #pragma unroll
  for (int nf = 0; nf < 4; ++nf) {
    float bb = b1[n0 + wn * 64 + nf * 16 + c];
    #pragma unroll
    for (int mf = 0; mf < 4; ++mf) {
      #pragma unroll
      for (int i = 0; i < 4; ++i) {
        int row = m0 + wm * 64 + mf * 16 + 4 * g + i;
        int col = n0 + wn * 64 + nf * 16 + c;
        float v = acc[mf][nf][i] + bb;
        H[(long)row * HID + col] = f2bf(fmaxf(v, 0.f));
      }
    }
  }
}

// ---------------- GEMM2 (params) fused with per-lane spline ----------------
// (R5 structure, verbatim: best measured 204us, ~93% of LDS-byte roofline.)
// M=8192, Npad=12288, K=1024. Tile 128x192 (4 features), 8 waves (2x4),
// wave = 64 rows x 48 cols. Dbuf 2-phase K-loop; register-light epilogue.
__global__ __launch_bounds__(512, 4) void k_gemm2_spline(
    const unsigned short* __restrict__ Hb, const unsigned short* __restrict__ W2T,
    const float* __restrict__ b2, const float* __restrict__ inp,
    float* __restrict__ outp, float* __restrict__ ladw) {
  __shared__ __align__(16) char sm[81920];  // 2 x (A 16KB + B 24KB)
  const int tid = threadIdx.x;
  const int lane = tid & 63, wid = tid >> 6;
  const int c = lane & 15, g = lane >> 4;
  const int wm = wid >> 2, wn = wid & 3;
  const long m0 = (long)blockIdx.x * 128;
  const int bn = blockIdx.y;
  const int n0 = bn * 192;  // padded-col base

  f32x4 zero = {0.f, 0.f, 0.f, 0.f};
  f32x4 acc[4][3];
  #pragma unroll
  for (int a = 0; a < 4; ++a)
    #pragma unroll
    for (int b = 0; b < 3; ++b) acc[a][b] = zero;

  // ---- precomputed staging state (hoisted out of K-loop) ----
  const char *gA0, *gA1, *gB0, *gB1, *gB2;
  int dA0, dA1, dB0, dB1, dB2;
  {
    int s0, s, row, kb;
    s0 = wid * 64;            s = s0 + lane; row = s >> 3; kb = (s & 7) ^ (row & 7);
    gA0 = (const char*)(Hb + (m0 + row) * 1024L + kb * 8); dA0 = s0 * 16;
    s0 = 512 + wid * 64;      s = s0 + lane; row = s >> 3; kb = (s & 7) ^ (row & 7);
    gA1 = (const char*)(Hb + (m0 + row) * 1024L + kb * 8); dA1 = s0 * 16;
    s0 = wid * 64;            s = s0 + lane; row = s >> 3; kb = (s & 7) ^ (row & 7);
    gB0 = (const char*)(W2T + (long)(n0 + row) * 1024L + kb * 8); dB0 = s0 * 16 + 16384;
    s0 = 512 + wid * 64;      s = s0 + lane; row = s >> 3; kb = (s & 7) ^ (row & 7);
    gB1 = (const char*)(W2T + (long)(n0 + row) * 1024L + kb * 8); dB1 = s0 * 16 + 16384;
    s0 = 1024 + wid * 64;     s = s0 + lane; row = s >> 3; kb = (s & 7) ^ (row & 7);
    gB2 = (const char*)(W2T + (long)(n0 + row) * 1024L + kb * 8); dB2 = s0 * 16 + 16384;
  }
  // ds_read byte offsets (within half-0 buffer), per [kk][frag]
  int oA[2][4], oB[2][3];
  #pragma unroll
  for (int kk = 0; kk < 2; ++kk) {
    int kbl = kk * 4 + g;
    #pragma unroll
    for (int mf = 0; mf < 4; ++mf) {
      int row = wm * 64 + mf * 16 + c;
      oA[kk][mf] = row * 128 + ((kbl ^ (row & 7)) << 4);
    }
    #pragma unroll
    for (int nf = 0; nf < 3; ++nf) {
      int col = wn * 48 + nf * 16 + c;
      oB[kk][nf] = col * 128 + ((kbl ^ (col & 7)) << 4) + 16384;
    }
  }

  #define G2_STAGE(HALF, IMM)                                        \
    {                                                                \
      gload16(gA0 + (IMM), sm + (HALF) * 40960 + dA0);               \
      gload16(gA1 + (IMM), sm + (HALF) * 40960 + dA1);               \
      gload16(gB0 + (IMM), sm + (HALF) * 40960 + dB0);               \
      gload16(gB1 + (IMM), sm + (HALF) * 40960 + dB1);               \
      gload16(gB2 + (IMM), sm + (HALF) * 40960 + dB2);               \
    }

  #define G2_BUMP(N) { gA0 += (N); gA1 += (N); gB0 += (N); gB1 += (N); gB2 += (N); }

  #define G2_COMP(HALF)                                                        \
    {                                                                          \
      _Pragma("unroll")                                                        \
      for (int kk = 0; kk < 2; ++kk) {                                         \
        bf16x8 av[4], bv[3];                                                   \
        _Pragma("unroll")                                                      \
        for (int mf = 0; mf < 4; ++mf)                                         \
          av[mf] = *(const bf16x8*)(sm + (HALF) * 40960 + oA[kk][mf]);         \
        _Pragma("unroll")                                                      \
        for (int nf = 0; nf < 3; ++nf)                                         \
          bv[nf] = *(const bf16x8*)(sm + (HALF) * 40960 + oB[kk][nf]);         \
        _Pragma("unroll")                                                      \
        for (int mf = 0; mf < 4; ++mf)                                         \
          _Pragma("unroll")                                                    \
          for (int nf = 0; nf < 3; ++nf)                                       \
            acc[mf][nf] = __builtin_amdgcn_mfma_f32_16x16x32_bf16(             \
                av[mf], bv[nf], acc[mf][nf], 0, 0, 0);                         \
      }                                                                        \
    }

  // prologue: stage ks=0 into half0; pointers then at ks=1 base
  G2_STAGE(0, 0);
  G2_BUMP(128);
  __syncthreads();
  // main: 7 iterations cover ks=0..13 compute, ks=1..14 stage
  for (int ks2 = 0; ks2 < 7; ++ks2) {
    G2_STAGE(1, 0);        // stage ks=2*ks2+1 -> half1
    G2_COMP(0);            // compute ks=2*ks2
    __syncthreads();
    G2_STAGE(0, 128);      // stage ks=2*ks2+2 -> half0
    G2_COMP(1);            // compute ks=2*ks2+1
    __syncthreads();
    G2_BUMP(256);
  }
  // tail: ks=14 (half0), ks=15 (half1)
  G2_STAGE(1, 0);          // stage ks=15 -> half1
  G2_COMP(0);              // compute ks=14
  __syncthreads();
  G2_COMP(1);              // compute ks=15
  __syncthreads();         // epilogue stripes overlay the double buffer

  // ---- epilogue: per-wave LDS stripes, wave-local sync only ----
  // stripe layout: [param k 0..15][row 0..63], k-stride 68 f32
  float* stA = (float*)(sm + wid * 8704);     // 4352 B
  float* stB = stA + 1088;                    // 4352 B
  const int t = bn * 4 + wn;                  // global transform-feature id
  const float* b2t = b2 + t * PPF;
  const float bw = b2t[c];
  const float bh = b2t[16 + c];
  const float bd = (c < 15) ? b2t[32 + c] : 0.f;
  const long r = m0 + wm * 64 + lane;
  float x = inp[r * FEAT + 2 * t];            // issue early

  // stage widths -> stA, heights -> stB (b128, conflict-free)
  #pragma unroll
  for (int mf = 0; mf < 4; ++mf) {
    f32x4 vw = acc[mf][0], vh = acc[mf][1];
    #pragma unroll
    for (int i = 0; i < 4; ++i) { vw[i] += bw; vh[i] += bh; }
    *(f32x4*)(stA + c * 68 + mf * 16 + 4 * g) = vw;
    *(f32x4*)(stB + c * 68 + mf * 16 + 4 * g) = vh;
  }

  float xc = fminf(fmaxf(x, -TBOUND), TBOUND);
  int idx = 0;
  float in_cw, in_w, in_ch, in_h;
  // ---- widths: softmax + fused cumsum/bin-search ----
  {
    float u[16];
    #pragma unroll
    for (int k = 0; k < 16; ++k) u[k] = stA[k * 68 + lane];
    float mx = u[0];
    #pragma unroll
    for (int k = 1; k < 16; ++k) mx = fmaxf(mx, u[k]);
    float e[16], s = 0.f;
    #pragma unroll
    for (int k = 0; k < 16; ++k) { e[k] = __expf(u[k] - mx); s += e[k]; }
    float inv = (1.f - MIN_W * 16.f) / s;
    float wk = fmaf(e[0], inv, MIN_W);
    float wsel = wk, cum = 0.f;
    in_cw = -TBOUND;
    #pragma unroll
    for (int k = 0; k < 15; ++k) {
      cum += wk;
      float knot = fmaf(2.f * TBOUND, cum, -TBOUND);
      float wk1 = fmaf(e[k + 1], inv, MIN_W);
      bool le = (knot <= xc);
      idx = le ? k + 1 : idx;
      in_cw = le ? knot : in_cw;
      wsel = le ? wk1 : wsel;
      wk = wk1;
    }
    in_w = 2.f * TBOUND * wsel;
  }
  // stage derivs -> stA (safe: same-wave, program-ordered after reads)
  #pragma unroll
  for (int mf = 0; mf < 4; ++mf) {
    f32x4 vd = acc[mf][2];
    #pragma unroll
    for (int i = 0; i < 4; ++i) vd[i] += bd;
    *(f32x4*)(stA + c * 68 + mf * 16 + 4 * g) = vd;
  }
  // ---- heights: softmax + select-at-idx ----
  {
    float u[16];
    #pragma unroll
    for (int k = 0; k < 16; ++k) u[k] = stB[k * 68 + lane];
    float mx = u[0];
    #pragma unroll
    for (int k = 1; k < 16; ++k) mx = fmaxf(mx, u[k]);
    float e[16], s = 0.f;
    #pragma unroll
    for (int k = 0; k < 16; ++k) { e[k] = __expf(u[k] - mx); s += e[k]; }
    float inv = (1.f - MIN_H * 16.f) / s;
    float hk = fmaf(e[0], inv, MIN_H);
    float hsel = hk, cum = 0.f;
    in_ch = -TBOUND;
    #pragma unroll
    for (int k = 0; k < 15; ++k) {
      cum += hk;
      float knot = fmaf(2.f * TBOUND, cum, -TBOUND);
      float hk1 = fmaf(e[k + 1], inv, MIN_H);
      bool pick = (idx == k + 1);
      in_ch = pick ? knot : in_ch;
      hsel = pick ? hk1 : hsel;
      hk = hk1;
    }
    in_h = 2.f * TBOUND * hsel;
  }
  // ---- derivs: 2 runtime-indexed LDS reads + 2 softplus ----
  float d0, d1;
  {
    int i0 = (idx > 0) ? idx - 1 : 0;
    int i1 = (idx < 15) ? idx : 14;
    float v0 = stA[i0 * 68 + lane];
    float v1 = stA[i1 * 68 + lane];
    float sp0 = (v0 > 0.f) ? (v0 + log1pf(__expf(-v0))) : log1pf(__expf(v0));
    float sp1 = (v1 > 0.f) ? (v1 + log1pf(__expf(-v1))) : log1pf(__expf(v1));
    d0 = (idx == 0) ? 1.f : (MIN_D + sp0);
    d1 = (idx == 15) ? 1.f : (MIN_D + sp1);
  }
  // ---- rational-quadratic eval ----
  float dlt = in_h / in_w;
  float th = (xc - in_cw) / in_w;
  float omt = 1.f - th, t1m = th * omt;
  float den = dlt + (d0 + d1 - 2.f * dlt) * t1m;
  float num = in_h * (dlt * th * th + d0 * t1m);
  float y = in_ch + num / den;
  float dn = dlt * dlt * (d1 * th * th + 2.f * dlt * t1m + d0 * omt * omt);
  float lad = __logf(dn) - 2.f * __logf(den);
  bool inside = (x >= -TBOUND) && (x <= TBOUND);
  y = inside ? y : x;
  lad = inside ? lad : 0.f;
  outp[r * FEAT + 2 * t] = y;
  ladw[r * NTR + t] = lad;
}

// ---------------- lad reduction: 256 -> 1 per batch row ----------------
__global__ void k_reduce_lad(const float* __restrict__ ladw,
                             float* __restrict__ lado) {
  int wid = threadIdx.x >> 6, lane = threadIdx.x & 63;
  long b = (long)blockIdx.x * 4 + wid;
  const float4* p = (const float4*)(ladw + b * NTR);
  float4 v = p[lane];
  float s = v.x + v.y + v.z + v.w;
  #pragma unroll
  for (int d = 1; d < 64; d <<= 1) s += __shfl_xor(s, d, 64);
  if (lane == 0) lado[b] = s;
}

extern "C" void kernel_launch(void* const* d_in, const int* in_sizes, int n_in,
                              void* d_out, int out_size, void* d_ws, size_t ws_size,
                              hipStream_t stream) {
  const float* inp = (const float*)d_in[0];
  const float* W1  = (const float*)d_in[1];
  const float* b1  = (const float*)d_in[2];
  const float* W2  = (const float*)d_in[3];
  const float* b2  = (const float*)d_in[4];
  float* outp = (float*)d_out;
  float* lado = outp + (long)BATCH * FEAT;

  // workspace layout (~52.5 MB)
  char* ws = (char*)d_ws;
  unsigned short* Hb   = (unsigned short*)(ws);              // 16,777,216 B
  unsigned short* idbf = (unsigned short*)(ws + 16777216);   //  4,194,304 B
  unsigned short* W1T  = (unsigned short*)(ws + 20971520);   //    524,288 B
  unsigned short* W2T  = (unsigned short*)(ws + 21495808);   // 25,165,824 B
  float*          ladw = (float*)(ws + 46661632);            //  8,388,608 B

  k_pack_all<<<dim3(8192), dim3(256), 0, stream>>>(inp, W1, W2, idbf, W1T, W2T, outp);
  k_gemm1<<<dim3(64, 8), dim3(256), 0, stream>>>(idbf, W1T, b1, Hb);
  k_gemm2_spline<<<dim3(64, 64), dim3(512), 0, stream>>>(Hb, W2T, b2, inp, outp, ladw);
  k_reduce_lad<<<dim3(2048), dim3(256), 0, stream>>>(ladw, lado);
}

// Round 12
// 223.494 us; speedup vs baseline: 2.1651x; 1.0241x over previous
//
#include <hip/hip_runtime.h>

#define BATCH 8192
#define FEAT  512
#define NID   256
#define NTR   256
#define HID   1024
#define PPF   47       // params per transform feature (3*16-1)
#define PPFP  48       // padded to 48
#define NOUT  (NTR*PPF)    // 12032
#define TBOUND 3.0f
#define MIN_W 0.001f
#define MIN_H 0.001f
#define MIN_D 0.001f

typedef __bf16 bf16x8 __attribute__((ext_vector_type(8)));
typedef float  f32x4  __attribute__((ext_vector_type(4)));

__device__ __forceinline__ unsigned short f2bf(float f) {
  unsigned u = __float_as_uint(f);
  u += 0x7FFFu + ((u >> 16) & 1u);   // RNE
  return (unsigned short)(u >> 16);
}

// async global->LDS, 16B per lane. LDS dest must be wave-uniform base
// (HW adds lane*16); global source is per-lane.
__device__ __forceinline__ void gload16(const void* g, void* l) {
  __builtin_amdgcn_global_load_lds(
      (const __attribute__((address_space(1))) void*)g,
      (__attribute__((address_space(3))) void*)l, 16, 0, 0);
}

// ---------------- fused pack kernel ----------------
// bid [0,4096):   inputs odd cols -> idbf (bf16); zero lado rows
// bid [4096,4160): W1 -> W1T transpose (bf16)
// bid [4160,7168): W2 -> W2T transpose+pad-remap (bf16)
// bid [7168,8192): zero pad column 47 of each 48-group
__global__ void k_pack_all(const float* __restrict__ in,
                           const float* __restrict__ W1,
                           const float* __restrict__ W2,
                           unsigned short* __restrict__ idbf,
                           unsigned short* __restrict__ W1T,
                           unsigned short* __restrict__ W2T,
                           float* __restrict__ lado) {
  const int bid = blockIdx.x;
  const int tid = threadIdx.x;
  if (bid < 4096) {
    int b = bid * 2 + (tid >> 7);
    int j4 = tid & 127;                       // float4 index within row
    float4 v = ((const float4*)(in + (long)b * FEAT))[j4];
    ushort2 h;
    h.x = f2bf(v.y);
    h.y = f2bf(v.w);
    ((ushort2*)(idbf + (long)b * NID))[j4] = h;
    if (tid == 0) {                           // zero lad accumulators
      lado[2 * bid] = 0.f;
      lado[2 * bid + 1] = 0.f;
    }
  } else if (bid < 4160) {
    __shared__ unsigned short tl[64][65];
    int i = bid - 4096;
    int n0 = (i & 15) * 64, k0 = (i >> 4) * 64;
    int c = tid & 63, r4 = tid >> 6;
    #pragma unroll
    for (int j = 0; j < 16; ++j) {
      int kk = r4 + j * 4;
      tl[kk][c] = f2bf(W1[(k0 + kk) * HID + n0 + c]);
    }
    __syncthreads();
    #pragma unroll
    for (int j = 0; j < 16; ++j) {
      int nn = r4 + j * 4;
      W1T[(n0 + nn) * NID + k0 + c] = tl[c][nn];
    }
  } else if (bid < 7168) {
    __shared__ unsigned short tl[64][65];
    int i = bid - 4160;
    int ns0 = (i % 188) * 64, k0 = (i / 188) * 64;
    int c = tid & 63, r4 = tid >> 6;
    #pragma unroll
    for (int j = 0; j < 16; ++j) {
      int kk = r4 + j * 4;
      tl[kk][c] = f2bf(W2[(k0 + kk) * (long)NOUT + ns0 + c]);
    }
    __syncthreads();
    #pragma unroll
    for (int j = 0; j < 16; ++j) {
      int nn = r4 + j * 4;
      int ns = ns0 + nn;
      int nd = (ns / PPF) * PPFP + (ns % PPF);
      W2T[(long)nd * HID + k0 + c] = tl[c][nn];
    }
  } else {
    int idx = (bid - 7168) * 256 + tid;       // 256 features * 1024 k
    int f = idx >> 10, k = idx & 1023;
    W2T[((long)(f * PPFP + PPF)) * HID + k] = 0;
  }
}

// ---------------- GEMM1: h = relu(idbf @ W1 + b1), bf16 out ----------------
// M=8192 K=256 N=1024, tiles 128x128, BK=64, 4 waves (2x2), dbuf 2-phase
__global__ __launch_bounds__(256, 2) void k_gemm1(
    const unsigned short* __restrict__ A, const unsigned short* __restrict__ Bw,
    const float* __restrict__ b1, unsigned short* __restrict__ H) {
  __shared__ __align__(16) char sm[65536];  // 2 x (A 16KB + B 16KB)
  const int tid = threadIdx.x;
  const int lane = tid & 63, wid = tid >> 6;
  const int c = lane & 15, g = lane >> 4;
  const int wm = wid >> 1, wn = wid & 1;
  const int m0 = blockIdx.x * 128, n0 = blockIdx.y * 128;

  f32x4 zero = {0.f, 0.f, 0.f, 0.f};
  f32x4 acc[4][4];
  #pragma unroll
  for (int a = 0; a < 4; ++a)
    #pragma unroll
    for (int b = 0; b < 4; ++b) acc[a][b] = zero;

  #define G1_STAGE(half, ks)                                                   \
    {                                                                          \
      char* bA = sm + (half) * 32768;                                          \
      char* bB = bA + 16384;                                                   \
      _Pragma("unroll")                                                        \
      for (int j = 0; j < 4; ++j) {                                            \
        int s0 = j * 256 + wid * 64;                                           \
        int s = s0 + lane;                                                     \
        int row = s >> 3, kb = (s & 7) ^ (row & 7);                            \
        gload16(A + (long)(m0 + row) * NID + (ks) * 64 + kb * 8, bA + s0 * 16);\
        gload16(Bw + (long)(n0 + row) * NID + (ks) * 64 + kb * 8, bB + s0 * 16);\
      }                                                                        \
    }

  G1_STAGE(0, 0);
  __syncthreads();
  for (int ks = 0; ks < 4; ++ks) {
    int cur = ks & 1;
    if (ks < 3) G1_STAGE(cur ^ 1, ks + 1);
    char* bA = sm + cur * 32768;
    char* bB = bA + 16384;
    #pragma unroll
    for (int kk = 0; kk < 2; ++kk) {
      bf16x8 av[4], bv[4];
      int kbl = kk * 4 + g;
      #pragma unroll
      for (int mf = 0; mf < 4; ++mf) {
        int row = wm * 64 + mf * 16 + c;
        av[mf] = *(const bf16x8*)(bA + row * 128 + ((kbl ^ (row & 7)) << 4));
      }
      #pragma unroll
      for (int nf = 0; nf < 4; ++nf) {
        int col = wn * 64 + nf * 16 + c;
        bv[nf] = *(const bf16x8*)(bB + col * 128 + ((kbl ^ (col & 7)) << 4));
      }
      #pragma unroll
      for (int mf = 0; mf < 4; ++mf)
        #pragma unroll
        for (int nf = 0; nf < 4; ++nf)
          acc[mf][nf] = __builtin_amdgcn_mfma_f32_16x16x32_bf16(
              av[mf], bv[nf], acc[mf][nf], 0, 0, 0);
    }
    __syncthreads();
  }
  #pragma unroll
  for (int nf = 0; nf < 4; ++nf) {
    float bb = b1[n0 + wn * 64 + nf * 16 + c];
    #pragma unroll
    for (int mf = 0; mf < 4; ++mf) {
      #pragma unroll
      for (int i = 0; i < 4; ++i) {
        int row = m0 + wm * 64 + mf * 16 + 4 * g + i;
        int col = n0 + wn * 64 + nf * 16 + c;
        float v = acc[mf][nf][i] + bb;
        H[(long)row * HID + col] = f2bf(fmaxf(v, 0.f));
      }
    }
  }
}

// ---------------- GEMM2 (params) fused with per-lane spline ----------------
// (R5 K-loop verbatim: 204us, ~94% of LDS-byte roofline.)
// M=8192, Npad=12288, K=1024. Tile 128x192 (4 features), 8 waves (2x4),
// wave = 64 rows x 48 cols. Epilogue additionally writes the identity
// column (float2 {y, id}) and block-reduces lad -> one atomicAdd per row.
__global__ __launch_bounds__(512, 4) void k_gemm2_spline(
    const unsigned short* __restrict__ Hb, const unsigned short* __restrict__ W2T,
    const float* __restrict__ b2, const float* __restrict__ inp,
    float* __restrict__ outp, float* __restrict__ lado) {
  __shared__ __align__(16) char sm[81920];  // 2 x (A 16KB + B 24KB)
  const int tid = threadIdx.x;
  const int lane = tid & 63, wid = tid >> 6;
  const int c = lane & 15, g = lane >> 4;
  const int wm = wid >> 2, wn = wid & 3;
  const long m0 = (long)blockIdx.x * 128;
  const int bn = blockIdx.y;
  const int n0 = bn * 192;  // padded-col base

  f32x4 zero = {0.f, 0.f, 0.f, 0.f};
  f32x4 acc[4][3];
  #pragma unroll
  for (int a = 0; a < 4; ++a)
    #pragma unroll
    for (int b = 0; b < 3; ++b) acc[a][b] = zero;

  // ---- precomputed staging state (hoisted out of K-loop) ----
  const char *gA0, *gA1, *gB0, *gB1, *gB2;
  int dA0, dA1, dB0, dB1, dB2;
  {
    int s0, s, row, kb;
    s0 = wid * 64;            s = s0 + lane; row = s >> 3; kb = (s & 7) ^ (row & 7);
    gA0 = (const char*)(Hb + (m0 + row) * 1024L + kb * 8); dA0 = s0 * 16;
    s0 = 512 + wid * 64;      s = s0 + lane; row = s >> 3; kb = (s & 7) ^ (row & 7);
    gA1 = (const char*)(Hb + (m0 + row) * 1024L + kb * 8); dA1 = s0 * 16;
    s0 = wid * 64;            s = s0 + lane; row = s >> 3; kb = (s & 7) ^ (row & 7);
    gB0 = (const char*)(W2T + (long)(n0 + row) * 1024L + kb * 8); dB0 = s0 * 16 + 16384;
    s0 = 512 + wid * 64;      s = s0 + lane; row = s >> 3; kb = (s & 7) ^ (row & 7);
    gB1 = (const char*)(W2T + (long)(n0 + row) * 1024L + kb * 8); dB1 = s0 * 16 + 16384;
    s0 = 1024 + wid * 64;     s = s0 + lane; row = s >> 3; kb = (s & 7) ^ (row & 7);
    gB2 = (const char*)(W2T + (long)(n0 + row) * 1024L + kb * 8); dB2 = s0 * 16 + 16384;
  }
  // ds_read byte offsets (within half-0 buffer), per [kk][frag]
  int oA[2][4], oB[2][3];
  #pragma unroll
  for (int kk = 0; kk < 2; ++kk) {
    int kbl = kk * 4 + g;
    #pragma unroll
    for (int mf = 0; mf < 4; ++mf) {
      int row = wm * 64 + mf * 16 + c;
      oA[kk][mf] = row * 128 + ((kbl ^ (row & 7)) << 4);
    }
    #pragma unroll
    for (int nf = 0; nf < 3; ++nf) {
      int col = wn * 48 + nf * 16 + c;
      oB[kk][nf] = col * 128 + ((kbl ^ (col & 7)) << 4) + 16384;
    }
  }

  #define G2_STAGE(HALF, IMM)                                        \
    {                                                                \
      gload16(gA0 + (IMM), sm + (HALF) * 40960 + dA0);               \
      gload16(gA1 + (IMM), sm + (HALF) * 40960 + dA1);               \
      gload16(gB0 + (IMM), sm + (HALF) * 40960 + dB0);               \
      gload16(gB1 + (IMM), sm + (HALF) * 40960 + dB1);               \
      gload16(gB2 + (IMM), sm + (HALF) * 40960 + dB2);               \
    }

  #define G2_BUMP(N) { gA0 += (N); gA1 += (N); gB0 += (N); gB1 += (N); gB2 += (N); }

  #define G2_COMP(HALF)                                                        \
    {                                                                          \
      _Pragma("unroll")                                                        \
      for (int kk = 0; kk < 2; ++kk) {                                         \
        bf16x8 av[4], bv[3];                                                   \
        _Pragma("unroll")                                                      \
        for (int mf = 0; mf < 4; ++mf)                                         \
          av[mf] = *(const bf16x8*)(sm + (HALF) * 40960 + oA[kk][mf]);         \
        _Pragma("unroll")                                                      \
        for (int nf = 0; nf < 3; ++nf)                                         \
          bv[nf] = *(const bf16x8*)(sm + (HALF) * 40960 + oB[kk][nf]);         \
        _Pragma("unroll")                                                      \
        for (int mf = 0; mf < 4; ++mf)                                         \
          _Pragma("unroll")                                                    \
          for (int nf = 0; nf < 3; ++nf)                                       \
            acc[mf][nf] = __builtin_amdgcn_mfma_f32_16x16x32_bf16(             \
                av[mf], bv[nf], acc[mf][nf], 0, 0, 0);                         \
      }                                                                        \
    }

  // prologue: stage ks=0 into half0; pointers then at ks=1 base
  G2_STAGE(0, 0);
  G2_BUMP(128);
  __syncthreads();
  // main: 7 iterations cover ks=0..13 compute, ks=1..14 stage
  for (int ks2 = 0; ks2 < 7; ++ks2) {
    G2_STAGE(1, 0);        // stage ks=2*ks2+1 -> half1
    G2_COMP(0);            // compute ks=2*ks2
    __syncthreads();
    G2_STAGE(0, 128);      // stage ks=2*ks2+2 -> half0
    G2_COMP(1);            // compute ks=2*ks2+1
    __syncthreads();
    G2_BUMP(256);
  }
  // tail: ks=14 (half0), ks=15 (half1)
  G2_STAGE(1, 0);          // stage ks=15 -> half1
  G2_COMP(0);              // compute ks=14
  __syncthreads();
  G2_COMP(1);              // compute ks=15
  __syncthreads();         // epilogue stripes overlay the double buffer

  // ---- epilogue: per-wave LDS stripes, wave-local sync only ----
  // stripe layout: [param k 0..15][row 0..63], k-stride 68 f32
  float* stA = (float*)(sm + wid * 8704);     // 4352 B
  float* stB = stA + 1088;                    // 4352 B
  const int t = bn * 4 + wn;                  // global transform-feature id
  const float* b2t = b2 + t * PPF;
  const float bw = b2t[c];
  const float bh = b2t[16 + c];
  const float bd = (c < 15) ? b2t[32 + c] : 0.f;
  const long r = m0 + wm * 64 + lane;
  float2 x2 = *(const float2*)(inp + r * FEAT + 2 * t);  // {transform, id}
  const float x = x2.x;

  // stage widths -> stA, heights -> stB (b128, conflict-free)
  #pragma unroll
  for (int mf = 0; mf < 4; ++mf) {
    f32x4 vw = acc[mf][0], vh = acc[mf][1];
    #pragma unroll
    for (int i = 0; i < 4; ++i) { vw[i] += bw; vh[i] += bh; }
    *(f32x4*)(stA + c * 68 + mf * 16 + 4 * g) = vw;
    *(f32x4*)(stB + c * 68 + mf * 16 + 4 * g) = vh;
  }

  float xc = fminf(fmaxf(x, -TBOUND), TBOUND);
  int idx = 0;
  float in_cw, in_w, in_ch, in_h;
  // ---- widths: softmax + fused cumsum/bin-search ----
  {
    float u[16];
    #pragma unroll
    for (int k = 0; k < 16; ++k) u[k] = stA[k * 68 + lane];
    float mx = u[0];
    #pragma unroll
    for (int k = 1; k < 16; ++k) mx = fmaxf(mx, u[k]);
    float e[16], s = 0.f;
    #pragma unroll
    for (int k = 0; k < 16; ++k) { e[k] = __expf(u[k] - mx); s += e[k]; }
    float inv = (1.f - MIN_W * 16.f) / s;
    float wk = fmaf(e[0], inv, MIN_W);
    float wsel = wk, cum = 0.f;
    in_cw = -TBOUND;
    #pragma unroll
    for (int k = 0; k < 15; ++k) {
      cum += wk;
      float knot = fmaf(2.f * TBOUND, cum, -TBOUND);
      float wk1 = fmaf(e[k + 1], inv, MIN_W);
      bool le = (knot <= xc);
      idx = le ? k + 1 : idx;
      in_cw = le ? knot : in_cw;
      wsel = le ? wk1 : wsel;
      wk = wk1;
    }
    in_w = 2.f * TBOUND * wsel;
  }
  // stage derivs -> stA (safe: same-wave, program-ordered after reads)
  #pragma unroll
  for (int mf = 0; mf < 4; ++mf) {
    f32x4 vd = acc[mf][2];
    #pragma unroll
    for (int i = 0; i < 4; ++i) vd[i] += bd;
    *(f32x4*)(stA + c * 68 + mf * 16 + 4 * g) = vd;
  }
  // ---- heights: softmax + select-at-idx ----
  {
    float u[16];
    #pragma unroll
    for (int k = 0; k < 16; ++k) u[k] = stB[k * 68 + lane];
    float mx = u[0];
    #pragma unroll
    for (int k = 1; k < 16; ++k) mx = fmaxf(mx, u[k]);
    float e[16], s = 0.f;
    #pragma unroll
    for (int k = 0; k < 16; ++k) { e[k] = __expf(u[k] - mx); s += e[k]; }
    float inv = (1.f - MIN_H * 16.f) / s;
    float hk = fmaf(e[0], inv, MIN_H);
    float hsel = hk, cum = 0.f;
    in_ch = -TBOUND;
    #pragma unroll
    for (int k = 0; k < 15; ++k) {
      cum += hk;
      float knot = fmaf(2.f * TBOUND, cum, -TBOUND);
      float hk1 = fmaf(e[k + 1], inv, MIN_H);
      bool pick = (idx == k + 1);
      in_ch = pick ? knot : in_ch;
      hsel = pick ? hk1 : hsel;
      hk = hk1;
    }
    in_h = 2.f * TBOUND * hsel;
  }
  // ---- derivs: 2 runtime-indexed LDS reads + 2 softplus ----
  float d0, d1;
  {
    int i0 = (idx > 0) ? idx - 1 : 0;
    int i1 = (idx < 15) ? idx : 14;
    float v0 = stA[i0 * 68 + lane];
    float v1 = stA[i1 * 68 + lane];
    float sp0 = (v0 > 0.f) ? (v0 + log1pf(__expf(-v0))) : log1pf(__expf(v0));
    float sp1 = (v1 > 0.f) ? (v1 + log1pf(__expf(-v1))) : log1pf(__expf(v1));
    d0 = (idx == 0) ? 1.f : (MIN_D + sp0);
    d1 = (idx == 15) ? 1.f : (MIN_D + sp1);
  }
  // ---- rational-quadratic eval ----
  float dlt = in_h / in_w;
  float th = (xc - in_cw) / in_w;
  float omt = 1.f - th, t1m = th * omt;
  float den = dlt + (d0 + d1 - 2.f * dlt) * t1m;
  float num = in_h * (dlt * th * th + d0 * t1m);
  float y = in_ch + num / den;
  float dn = dlt * dlt * (d1 * th * th + 2.f * dlt * t1m + d0 * omt * omt);
  float lad = __logf(dn) - 2.f * __logf(den);
  bool inside = (x >= -TBOUND) && (x <= TBOUND);
  y = inside ? y : x;
  lad = inside ? lad : 0.f;
  // fused output: {spline(transform), identity} in one 8B write
  float2 o; o.x = y; o.y = x2.y;
  *(float2*)(outp + r * FEAT + 2 * t) = o;

  // ---- block-local lad reduce (4 features/row) + 1 atomic per row ----
  float* ldr = (float*)(sm + 71680);          // [128][5] f32 (pad-5)
  ldr[(wm * 64 + lane) * 5 + wn] = lad;
  __syncthreads();
  if (tid < 128) {
    float s = ldr[tid * 5 + 0] + ldr[tid * 5 + 1] +
              ldr[tid * 5 + 2] + ldr[tid * 5 + 3];
    atomicAdd(&lado[m0 + tid], s);
  }
}

extern "C" void kernel_launch(void* const* d_in, const int* in_sizes, int n_in,
                              void* d_out, int out_size, void* d_ws, size_t ws_size,
                              hipStream_t stream) {
  const float* inp = (const float*)d_in[0];
  const float* W1  = (const float*)d_in[1];
  const float* b1  = (const float*)d_in[2];
  const float* W2  = (const float*)d_in[3];
  const float* b2  = (const float*)d_in[4];
  float* outp = (float*)d_out;
  float* lado = outp + (long)BATCH * FEAT;

  // workspace layout (~46.7 MB)
  char* ws = (char*)d_ws;
  unsigned short* Hb   = (unsigned short*)(ws);              // 16,777,216 B
  unsigned short* idbf = (unsigned short*)(ws + 16777216);   //  4,194,304 B
  unsigned short* W1T  = (unsigned short*)(ws + 20971520);   //    524,288 B
  unsigned short* W2T  = (unsigned short*)(ws + 21495808);   // 25,165,824 B

  k_pack_all<<<dim3(8192), dim3(256), 0, stream>>>(inp, W1, W2, idbf, W1T, W2T, lado);
  k_gemm1<<<dim3(64, 8), dim3(256), 0, stream>>>(idbf, W1T, b1, Hb);
  k_gemm2_spline<<<dim3(64, 64), dim3(512), 0, stream>>>(Hb, W2T, b2, inp, outp, lado);
}